// Round 1
// baseline (411.652 us; speedup 1.0000x reference)
//
#include <hip/hip_runtime.h>
#include <hip/hip_bf16.h>
#include <stdint.h>

// GQA prefill, all GEMM-shaped work on bf16 MFMA (16x16x32), fp32 accum.
// B=2 S=2048 E=2048 H=32 KVH=8 D=64 G=4.

#define S_LEN 2048
#define EMB   2048
#define NH    32
#define NKVH  8
#define HD    64
#define MTOT  4096            // B*S
#define NQKV  3072            // E + 2*KVH*D
#define KDIM  2048

typedef __attribute__((ext_vector_type(8))) short short8;
typedef __attribute__((ext_vector_type(4))) float f32x4;

__device__ __forceinline__ unsigned short f2bf(float x) {
    unsigned int u = __builtin_bit_cast(unsigned int, x);
    u = (u + 0x7FFFu + ((u >> 16) & 1u)) >> 16;   // RTN-even
    return (unsigned short)u;
}

// ---------------- fp32 -> bf16 elementwise (X) ----------------
__global__ void cvt_x(const float* __restrict__ x, unsigned short* __restrict__ o, int n4) {
    int stride = gridDim.x * blockDim.x;
    for (int i = blockIdx.x * blockDim.x + threadIdx.x; i < n4; i += stride) {
        float4 v = ((const float4*)x)[i];
        ushort4 r;
        r.x = f2bf(v.x); r.y = f2bf(v.y); r.z = f2bf(v.z); r.w = f2bf(v.w);
        ((ushort4*)o)[i] = r;
    }
}

__global__ void cat_bias(const float* __restrict__ bq, const float* __restrict__ bk,
                         const float* __restrict__ bv, float* __restrict__ o) {
    int i = blockIdx.x * blockDim.x + threadIdx.x;
    if (i < EMB) o[i] = bq[i];
    else if (i < EMB + 512) o[i] = bk[i - EMB];
    else if (i < NQKV) o[i] = bv[i - EMB - 512];
}

// --------- transpose fp32 [K=2048][N] -> bf16 [N][2048] (+row offset) ---------
__global__ void transpose_w(const float* __restrict__ src, unsigned short* __restrict__ dst,
                            int N, int rowOfs) {
    __shared__ float t[64][65];
    int n0 = blockIdx.x * 64, k0 = blockIdx.y * 64;
    int c = threadIdx.x & 63, r0 = threadIdx.x >> 6;
    #pragma unroll
    for (int r = r0; r < 64; r += 4) t[r][c] = src[(size_t)(k0 + r) * N + n0 + c];
    __syncthreads();
    #pragma unroll
    for (int r = r0; r < 64; r += 4)
        dst[(size_t)(rowOfs + n0 + r) * KDIM + k0 + c] = f2bf(t[c][r]);
}

// --------- transpose V slice of QKV -> Vt[b][kvh][d][s] (bf16) ---------
__global__ void transpose_v(const unsigned short* __restrict__ qkv, unsigned short* __restrict__ vt) {
    __shared__ unsigned short t[64][72];
    int s0 = blockIdx.x * 64; int kvh = blockIdx.y; int b = blockIdx.z;
    int c = threadIdx.x & 63, r0 = threadIdx.x >> 6;
    #pragma unroll
    for (int r = r0; r < 64; r += 4)
        t[r][c] = qkv[(size_t)(b * S_LEN + s0 + r) * NQKV + (EMB + NKVH * HD) + kvh * HD + c];
    __syncthreads();
    #pragma unroll
    for (int r = r0; r < 64; r += 4)
        vt[(size_t)((b * NKVH + kvh) * HD + r) * S_LEN + s0 + c] = t[c][r];
}

// --------- bf16 GEMM: A[M][2048] * Bt[N][2048]^T + bias -> C[M][N] ---------
// 128x128 tile, BK=32, 4 waves (2x2 of 64x64), global_load_lds width 16.
template <bool OUT_BF16>
__global__ __launch_bounds__(256) void gemm_bt(const unsigned short* __restrict__ A,
                                               const unsigned short* __restrict__ Bt,
                                               const float* __restrict__ bias,
                                               void* __restrict__ Cout, int N) {
    __shared__ __align__(16) unsigned short As[128 * 32];
    __shared__ __align__(16) unsigned short Bs[128 * 32];
    const int t = threadIdx.x;
    const int lane = t & 63;
    const int l15 = lane & 15, hi = lane >> 4;
    const int w = t >> 6;
    const int wm = (w >> 1) * 64, wn = (w & 1) * 64;
    const int m0 = blockIdx.y * 128, n0 = blockIdx.x * 128;

    const int srow = t >> 2, scol = (t & 3) * 8;
    const unsigned short* ag0 = A + (size_t)(m0 + srow) * KDIM + scol;
    const unsigned short* ag1 = ag0 + (size_t)64 * KDIM;
    const unsigned short* bg0 = Bt + (size_t)(n0 + srow) * KDIM + scol;
    const unsigned short* bg1 = bg0 + (size_t)64 * KDIM;

    f32x4 acc[4][4] = {};

    for (int k0 = 0; k0 < KDIM; k0 += 32) {
        __builtin_amdgcn_global_load_lds((const __attribute__((address_space(1))) void*)(ag0 + k0),
                                         (__attribute__((address_space(3))) void*)(As + t * 8), 16, 0, 0);
        __builtin_amdgcn_global_load_lds((const __attribute__((address_space(1))) void*)(ag1 + k0),
                                         (__attribute__((address_space(3))) void*)(As + 2048 + t * 8), 16, 0, 0);
        __builtin_amdgcn_global_load_lds((const __attribute__((address_space(1))) void*)(bg0 + k0),
                                         (__attribute__((address_space(3))) void*)(Bs + t * 8), 16, 0, 0);
        __builtin_amdgcn_global_load_lds((const __attribute__((address_space(1))) void*)(bg1 + k0),
                                         (__attribute__((address_space(3))) void*)(Bs + 2048 + t * 8), 16, 0, 0);
        __syncthreads();
        short8 af[4], bf[4];
        #pragma unroll
        for (int m = 0; m < 4; m++)
            af[m] = *(const short8*)(As + (wm + m * 16 + l15) * 32 + hi * 8);
        #pragma unroll
        for (int n = 0; n < 4; n++)
            bf[n] = *(const short8*)(Bs + (wn + n * 16 + l15) * 32 + hi * 8);
        #pragma unroll
        for (int m = 0; m < 4; m++)
            #pragma unroll
            for (int n = 0; n < 4; n++)
                acc[m][n] = __builtin_amdgcn_mfma_f32_16x16x32_bf16(af[m], bf[n], acc[m][n], 0, 0, 0);
        __syncthreads();
    }

    #pragma unroll
    for (int m = 0; m < 4; m++) {
        int row = m0 + wm + m * 16 + hi * 4;
        #pragma unroll
        for (int n = 0; n < 4; n++) {
            int col = n0 + wn + n * 16 + l15;
            float bb = bias[col];
            #pragma unroll
            for (int i = 0; i < 4; i++) {
                float v = acc[m][n][i] + bb;
                if (OUT_BF16) ((unsigned short*)Cout)[(size_t)(row + i) * N + col] = f2bf(v);
                else          ((float*)Cout)[(size_t)(row + i) * N + col] = v;
            }
        }
    }
}

// --------- flash attention: 4 waves x 32 q-rows, KV tile 64 ---------
__global__ __launch_bounds__(256) void attn(const unsigned short* __restrict__ qkv,
                                            const unsigned short* __restrict__ vt,
                                            unsigned short* __restrict__ out) {
    constexpr float LOG2E = 1.4426950408889634f;
    const int qt = blockIdx.x, h = blockIdx.y, b = blockIdx.z;
    const int kvh = h >> 2;                 // G=4 consecutive q heads per kv head
    const int t = threadIdx.x, lane = t & 63, w = t >> 6;
    const int l15 = lane & 15, hi = lane >> 4;

    __shared__ __align__(16) unsigned short p_lds[4][32][88];  // stride 176B: 16B-aligned, 2-way banks (free)

    const int qrow0 = b * S_LEN + qt * 128 + w * 32;
    short8 qf[2][2];
    #pragma unroll
    for (int m = 0; m < 2; m++)
        #pragma unroll
        for (int ks = 0; ks < 2; ks++)
            qf[m][ks] = *(const short8*)(qkv + (size_t)(qrow0 + m * 16 + l15) * NQKV + h * HD + ks * 32 + hi * 8);

    f32x4 o[2][4] = {};
    f32x4 mrun[2], lrun[2];
    #pragma unroll
    for (int m = 0; m < 2; m++)
        #pragma unroll
        for (int i = 0; i < 4; i++) { mrun[m][i] = -__builtin_inff(); lrun[m][i] = 0.f; }

    const unsigned short* kbase = qkv + (size_t)b * S_LEN * NQKV + EMB + kvh * HD;
    const unsigned short* vbase = vt + (size_t)(b * NKVH + kvh) * HD * S_LEN;

    for (int kv0 = 0; kv0 < S_LEN; kv0 += 64) {
        // ---- scores = 0.125 * Q Kt ----
        f32x4 sc[2][4] = {};
        #pragma unroll
        for (int ks = 0; ks < 2; ks++) {
            short8 kf[4];
            #pragma unroll
            for (int n = 0; n < 4; n++)
                kf[n] = *(const short8*)(kbase + (size_t)(kv0 + n * 16 + l15) * NQKV + ks * 32 + hi * 8);
            #pragma unroll
            for (int m = 0; m < 2; m++)
                #pragma unroll
                for (int n = 0; n < 4; n++)
                    sc[m][n] = __builtin_amdgcn_mfma_f32_16x16x32_bf16(qf[m][ks], kf[n], sc[m][n], 0, 0, 0);
        }
        #pragma unroll
        for (int m = 0; m < 2; m++)
            #pragma unroll
            for (int n = 0; n < 4; n++)
                sc[m][n] = sc[m][n] * 0.125f;

        // ---- online softmax (rows spread over 16-lane groups) ----
        f32x4 tmx[2];
        #pragma unroll
        for (int m = 0; m < 2; m++)
            #pragma unroll
            for (int i = 0; i < 4; i++)
                tmx[m][i] = fmaxf(fmaxf(sc[m][0][i], sc[m][1][i]), fmaxf(sc[m][2][i], sc[m][3][i]));
        #pragma unroll
        for (int mask = 1; mask <= 8; mask <<= 1)
            #pragma unroll
            for (int m = 0; m < 2; m++)
                #pragma unroll
                for (int i = 0; i < 4; i++)
                    tmx[m][i] = fmaxf(tmx[m][i], __shfl_xor(tmx[m][i], mask));

        f32x4 fac[2], mnew[2], ts[2];
        #pragma unroll
        for (int m = 0; m < 2; m++)
            #pragma unroll
            for (int i = 0; i < 4; i++) {
                mnew[m][i] = fmaxf(mrun[m][i], tmx[m][i]);
                fac[m][i] = exp2f((mrun[m][i] - mnew[m][i]) * LOG2E);
                mrun[m][i] = mnew[m][i];
                ts[m][i] = 0.f;
            }
        #pragma unroll
        for (int m = 0; m < 2; m++)
            #pragma unroll
            for (int n = 0; n < 4; n++)
                #pragma unroll
                for (int i = 0; i < 4; i++) {
                    float p = exp2f((sc[m][n][i] - mnew[m][i]) * LOG2E);
                    sc[m][n][i] = p;
                    ts[m][i] += p;
                }
        #pragma unroll
        for (int mask = 1; mask <= 8; mask <<= 1)
            #pragma unroll
            for (int m = 0; m < 2; m++)
                #pragma unroll
                for (int i = 0; i < 4; i++)
                    ts[m][i] += __shfl_xor(ts[m][i], mask);
        #pragma unroll
        for (int m = 0; m < 2; m++)
            #pragma unroll
            for (int i = 0; i < 4; i++)
                lrun[m][i] = lrun[m][i] * fac[m][i] + ts[m][i];
        #pragma unroll
        for (int m = 0; m < 2; m++)
            #pragma unroll
            for (int nd = 0; nd < 4; nd++)
                #pragma unroll
                for (int i = 0; i < 4; i++)
                    o[m][nd][i] *= fac[m][i];

        // ---- P (C-layout) -> LDS -> A-layout ----
        #pragma unroll
        for (int m = 0; m < 2; m++)
            #pragma unroll
            for (int n = 0; n < 4; n++)
                #pragma unroll
                for (int i = 0; i < 4; i++)
                    p_lds[w][m * 16 + hi * 4 + i][n * 16 + l15] = f2bf(sc[m][n][i]);

        // ---- O += P V ----
        #pragma unroll
        for (int ks = 0; ks < 2; ks++) {
            short8 vf[4], ap[2];
            #pragma unroll
            for (int nd = 0; nd < 4; nd++)
                vf[nd] = *(const short8*)(vbase + (size_t)(nd * 16 + l15) * S_LEN + kv0 + ks * 32 + hi * 8);
            #pragma unroll
            for (int m = 0; m < 2; m++)
                ap[m] = *(const short8*)(&p_lds[w][m * 16 + l15][ks * 32 + hi * 8]);
            #pragma unroll
            for (int m = 0; m < 2; m++)
                #pragma unroll
                for (int nd = 0; nd < 4; nd++)
                    o[m][nd] = __builtin_amdgcn_mfma_f32_16x16x32_bf16(ap[m], vf[nd], o[m][nd], 0, 0, 0);
        }
    }

    #pragma unroll
    for (int m = 0; m < 2; m++) {
        float inv[4];
        #pragma unroll
        for (int i = 0; i < 4; i++) inv[i] = 1.0f / lrun[m][i];
        #pragma unroll
        for (int nd = 0; nd < 4; nd++)
            #pragma unroll
            for (int i = 0; i < 4; i++)
                out[(size_t)(qrow0 + m * 16 + hi * 4 + i) * EMB + h * HD + nd * 16 + l15] =
                    f2bf(o[m][nd][i] * inv[i]);
    }
}

extern "C" void kernel_launch(void* const* d_in, const int* in_sizes, int n_in,
                              void* d_out, int out_size, void* d_ws, size_t ws_size,
                              hipStream_t stream) {
    const float* datas = (const float*)d_in[0];
    const float* Wq = (const float*)d_in[1];
    const float* bq = (const float*)d_in[2];
    const float* Wk = (const float*)d_in[3];
    const float* bk = (const float*)d_in[4];
    const float* Wv = (const float*)d_in[5];
    const float* bv = (const float*)d_in[6];
    const float* Wo = (const float*)d_in[7];
    const float* bo = (const float*)d_in[8];
    float* out = (float*)d_out;

    char* ws = (char*)d_ws;
    unsigned short* Xb = (unsigned short*)ws;      ws += (size_t)MTOT * KDIM * 2;          // 16.8 MB
    unsigned short* Wqkvt = (unsigned short*)ws;   ws += (size_t)NQKV * KDIM * 2;          // 12.6 MB
    unsigned short* Wot = (unsigned short*)ws;     ws += (size_t)EMB * KDIM * 2;           // 8.4 MB
    float* biasq = (float*)ws;                     ws += (size_t)NQKV * 4;                 // 12 KB
    unsigned short* QKV = (unsigned short*)ws;     ws += (size_t)MTOT * NQKV * 2;          // 25.2 MB
    unsigned short* Vt = (unsigned short*)ws;      ws += (size_t)2 * NKVH * HD * S_LEN * 2;// 4.2 MB
    unsigned short* AO = (unsigned short*)ws;      ws += (size_t)MTOT * EMB * 2;           // 16.8 MB

    cvt_x<<<2048, 256, 0, stream>>>(datas, Xb, MTOT * KDIM / 4);
    cat_bias<<<NQKV / 256, 256, 0, stream>>>(bq, bk, bv, biasq);
    transpose_w<<<dim3(EMB / 64, KDIM / 64), 256, 0, stream>>>(Wq, Wqkvt, EMB, 0);
    transpose_w<<<dim3(512 / 64, KDIM / 64), 256, 0, stream>>>(Wk, Wqkvt, 512, EMB);
    transpose_w<<<dim3(512 / 64, KDIM / 64), 256, 0, stream>>>(Wv, Wqkvt, 512, EMB + 512);
    transpose_w<<<dim3(EMB / 64, KDIM / 64), 256, 0, stream>>>(Wo, Wot, EMB, 0);

    gemm_bt<true><<<dim3(NQKV / 128, MTOT / 128), 256, 0, stream>>>(Xb, Wqkvt, biasq, QKV, NQKV);
    transpose_v<<<dim3(S_LEN / 64, NKVH, 2), 256, 0, stream>>>(QKV, Vt);
    attn<<<dim3(S_LEN / 128, NH, 2), 256, 0, stream>>>(QKV, Vt, AO);
    gemm_bt<false><<<dim3(EMB / 128, MTOT / 128), 256, 0, stream>>>(AO, Wot, bo, out, EMB);
}

// Round 2
// 388.101 us; speedup vs baseline: 1.0607x; 1.0607x over previous
//
#include <hip/hip_runtime.h>
#include <hip/hip_bf16.h>
#include <stdint.h>

// GQA prefill, all GEMM-shaped work on bf16 MFMA (16x16x32), fp32 accum.
// B=2 S=2048 E=2048 H=32 KVH=8 D=64 G=4.
// R2: attn rewritten with swapped QK^T (col=q, row=k) -> lane-local softmax,
//     in-register P repack (cvt_pk_bf16 + bpermute), defer-max, zero LDS.

#define S_LEN 2048
#define EMB   2048
#define NH    32
#define NKVH  8
#define HD    64
#define MTOT  4096            // B*S
#define NQKV  3072            // E + 2*KVH*D
#define KDIM  2048

typedef __attribute__((ext_vector_type(8))) short short8;
typedef __attribute__((ext_vector_type(4))) float f32x4;
typedef __attribute__((ext_vector_type(4))) unsigned int u32x4;
typedef unsigned int u32;

__device__ __forceinline__ unsigned short f2bf(float x) {
    unsigned int u = __builtin_bit_cast(unsigned int, x);
    u = (u + 0x7FFFu + ((u >> 16) & 1u)) >> 16;   // RTN-even
    return (unsigned short)u;
}

// v_cvt_pk_bf16_f32: low16 = bf16(a), high16 = bf16(b)
__device__ __forceinline__ u32 cvtpk_bf16(float a, float b) {
    u32 r;
    asm("v_cvt_pk_bf16_f32 %0, %1, %2" : "=v"(r) : "v"(a), "v"(b));
    return r;
}

// ---------------- fp32 -> bf16 elementwise (X) ----------------
__global__ void cvt_x(const float* __restrict__ x, unsigned short* __restrict__ o, int n4) {
    int stride = gridDim.x * blockDim.x;
    for (int i = blockIdx.x * blockDim.x + threadIdx.x; i < n4; i += stride) {
        float4 v = ((const float4*)x)[i];
        ushort4 r;
        r.x = f2bf(v.x); r.y = f2bf(v.y); r.z = f2bf(v.z); r.w = f2bf(v.w);
        ((ushort4*)o)[i] = r;
    }
}

__global__ void cat_bias(const float* __restrict__ bq, const float* __restrict__ bk,
                         const float* __restrict__ bv, float* __restrict__ o) {
    int i = blockIdx.x * blockDim.x + threadIdx.x;
    if (i < EMB) o[i] = bq[i];
    else if (i < EMB + 512) o[i] = bk[i - EMB];
    else if (i < NQKV) o[i] = bv[i - EMB - 512];
}

// --------- transpose fp32 [K=2048][N] -> bf16 [N][2048] (+row offset) ---------
__global__ void transpose_w(const float* __restrict__ src, unsigned short* __restrict__ dst,
                            int N, int rowOfs) {
    __shared__ float t[64][65];
    int n0 = blockIdx.x * 64, k0 = blockIdx.y * 64;
    int c = threadIdx.x & 63, r0 = threadIdx.x >> 6;
    #pragma unroll
    for (int r = r0; r < 64; r += 4) t[r][c] = src[(size_t)(k0 + r) * N + n0 + c];
    __syncthreads();
    #pragma unroll
    for (int r = r0; r < 64; r += 4)
        dst[(size_t)(rowOfs + n0 + r) * KDIM + k0 + c] = f2bf(t[c][r]);
}

// --------- transpose V slice of QKV -> Vt[b][kvh][d][s] (bf16) ---------
__global__ void transpose_v(const unsigned short* __restrict__ qkv, unsigned short* __restrict__ vt) {
    __shared__ unsigned short t[64][72];
    int s0 = blockIdx.x * 64; int kvh = blockIdx.y; int b = blockIdx.z;
    int c = threadIdx.x & 63, r0 = threadIdx.x >> 6;
    #pragma unroll
    for (int r = r0; r < 64; r += 4)
        t[r][c] = qkv[(size_t)(b * S_LEN + s0 + r) * NQKV + (EMB + NKVH * HD) + kvh * HD + c];
    __syncthreads();
    #pragma unroll
    for (int r = r0; r < 64; r += 4)
        vt[(size_t)((b * NKVH + kvh) * HD + r) * S_LEN + s0 + c] = t[c][r];
}

// --------- bf16 GEMM: A[M][2048] * Bt[N][2048]^T + bias -> C[M][N] ---------
template <bool OUT_BF16>
__global__ __launch_bounds__(256) void gemm_bt(const unsigned short* __restrict__ A,
                                               const unsigned short* __restrict__ Bt,
                                               const float* __restrict__ bias,
                                               void* __restrict__ Cout, int N) {
    __shared__ __align__(16) unsigned short As[128 * 32];
    __shared__ __align__(16) unsigned short Bs[128 * 32];
    const int t = threadIdx.x;
    const int lane = t & 63;
    const int l15 = lane & 15, hi = lane >> 4;
    const int w = t >> 6;
    const int wm = (w >> 1) * 64, wn = (w & 1) * 64;
    const int m0 = blockIdx.y * 128, n0 = blockIdx.x * 128;

    const int srow = t >> 2, scol = (t & 3) * 8;
    const unsigned short* ag0 = A + (size_t)(m0 + srow) * KDIM + scol;
    const unsigned short* ag1 = ag0 + (size_t)64 * KDIM;
    const unsigned short* bg0 = Bt + (size_t)(n0 + srow) * KDIM + scol;
    const unsigned short* bg1 = bg0 + (size_t)64 * KDIM;

    f32x4 acc[4][4] = {};

    for (int k0 = 0; k0 < KDIM; k0 += 32) {
        __builtin_amdgcn_global_load_lds((const __attribute__((address_space(1))) void*)(ag0 + k0),
                                         (__attribute__((address_space(3))) void*)(As + t * 8), 16, 0, 0);
        __builtin_amdgcn_global_load_lds((const __attribute__((address_space(1))) void*)(ag1 + k0),
                                         (__attribute__((address_space(3))) void*)(As + 2048 + t * 8), 16, 0, 0);
        __builtin_amdgcn_global_load_lds((const __attribute__((address_space(1))) void*)(bg0 + k0),
                                         (__attribute__((address_space(3))) void*)(Bs + t * 8), 16, 0, 0);
        __builtin_amdgcn_global_load_lds((const __attribute__((address_space(1))) void*)(bg1 + k0),
                                         (__attribute__((address_space(3))) void*)(Bs + 2048 + t * 8), 16, 0, 0);
        __syncthreads();
        short8 af[4], bf[4];
        #pragma unroll
        for (int m = 0; m < 4; m++)
            af[m] = *(const short8*)(As + (wm + m * 16 + l15) * 32 + hi * 8);
        #pragma unroll
        for (int n = 0; n < 4; n++)
            bf[n] = *(const short8*)(Bs + (wn + n * 16 + l15) * 32 + hi * 8);
        #pragma unroll
        for (int m = 0; m < 4; m++)
            #pragma unroll
            for (int n = 0; n < 4; n++)
                acc[m][n] = __builtin_amdgcn_mfma_f32_16x16x32_bf16(af[m], bf[n], acc[m][n], 0, 0, 0);
        __syncthreads();
    }

    #pragma unroll
    for (int m = 0; m < 4; m++) {
        int row = m0 + wm + m * 16 + hi * 4;
        #pragma unroll
        for (int n = 0; n < 4; n++) {
            int col = n0 + wn + n * 16 + l15;
            float bb = bias[col];
            #pragma unroll
            for (int i = 0; i < 4; i++) {
                float v = acc[m][n][i] + bb;
                if (OUT_BF16) ((unsigned short*)Cout)[(size_t)(row + i) * N + col] = f2bf(v);
                else          ((float*)Cout)[(size_t)(row + i) * N + col] = v;
            }
        }
    }
}

// --------- flash attention: swapped QK^T, lane-local softmax, no LDS ---------
// Per wave: 32 q rows (2 n-tiles of 16), KV tile 64 (4 m-tiles of 16).
// QK^T: sc[mt][nt] = mfma(K,Q): row k = mt*16+hi*4+i, col q = nt*16+l15.
// PV:   o[dt][nt]  = mfma(Vt,P): row d = dt*16+hi*4+i, col q = nt*16+l15.
__global__ __launch_bounds__(256) void attn(const unsigned short* __restrict__ qkv,
                                            const unsigned short* __restrict__ vt,
                                            unsigned short* __restrict__ out) {
    constexpr float CEXP = 0.125f * 1.4426950408889634f;   // scale * log2(e)
    const int qt = blockIdx.x, h = blockIdx.y, b = blockIdx.z;
    const int kvh = h >> 2;
    const int t = threadIdx.x, lane = t & 63, w = t >> 6;
    const int l15 = lane & 15, hi = lane >> 4;

    // bpermute source lanes for the P repack (byte addresses for __shfl are lane ids)
    const int grpA = ((hi & 1) << 1) | (hi >> 1);
    const int laneA = l15 + grpA * 16;
    const int laneB = laneA ^ 16;
    const bool top = hi >= 2;

    const int qrow0 = b * S_LEN + qt * 128 + w * 32;
    short8 qf[2][2];  // [nt][ks]
    #pragma unroll
    for (int nt = 0; nt < 2; nt++)
        #pragma unroll
        for (int ks = 0; ks < 2; ks++)
            qf[nt][ks] = *(const short8*)(qkv + (size_t)(qrow0 + nt * 16 + l15) * NQKV + h * HD + ks * 32 + hi * 8);

    f32x4 o[4][2] = {};              // [dt][nt]
    float mrn[2] = {-__builtin_inff(), -__builtin_inff()};
    float lrn[2] = {0.f, 0.f};

    const unsigned short* kbase = qkv + (size_t)b * S_LEN * NQKV + EMB + kvh * HD;
    const unsigned short* vbase = vt + (size_t)(b * NKVH + kvh) * HD * S_LEN;

    for (int kv0 = 0; kv0 < S_LEN; kv0 += 64) {
        // ---- S^T = K Q^T ----
        f32x4 sc[4][2] = {};         // [mt(k)][nt(q)]
        #pragma unroll
        for (int ks = 0; ks < 2; ks++) {
            short8 kf[4];
            #pragma unroll
            for (int mt = 0; mt < 4; mt++)
                kf[mt] = *(const short8*)(kbase + (size_t)(kv0 + mt * 16 + l15) * NQKV + ks * 32 + hi * 8);
            #pragma unroll
            for (int mt = 0; mt < 4; mt++)
                #pragma unroll
                for (int nt = 0; nt < 2; nt++)
                    sc[mt][nt] = __builtin_amdgcn_mfma_f32_16x16x32_bf16(kf[mt], qf[nt][ks], sc[mt][nt], 0, 0, 0);
        }

        // ---- online softmax, lane-local over k ----
        u32 w0[4][2], w1[4][2];      // packed bf16 P pairs [mt][nt]
        #pragma unroll
        for (int nt = 0; nt < 2; nt++) {
            float mx = sc[0][nt][0];
            #pragma unroll
            for (int mt = 0; mt < 4; mt++)
                #pragma unroll
                for (int i = 0; i < 4; i++)
                    mx = fmaxf(mx, sc[mt][nt][i]);
            mx = fmaxf(mx, __shfl_xor(mx, 16));
            mx = fmaxf(mx, __shfl_xor(mx, 32));
            // defer-max: only rescale when the new tile max exceeds by >16 (raw units)
            if (!__all(mx - mrn[nt] <= 16.f)) {
                float mn = fmaxf(mrn[nt], mx);
                float fac = exp2f((mrn[nt] - mn) * CEXP);
                lrn[nt] *= fac;
                #pragma unroll
                for (int dt = 0; dt < 4; dt++)
                    o[dt][nt] *= fac;
                mrn[nt] = mn;
            }
            float s = 0.f;
            #pragma unroll
            for (int mt = 0; mt < 4; mt++) {
                #pragma unroll
                for (int i = 0; i < 4; i++) {
                    float p = exp2f((sc[mt][nt][i] - mrn[nt]) * CEXP);
                    sc[mt][nt][i] = p;
                    s += p;
                }
                w0[mt][nt] = cvtpk_bf16(sc[mt][nt][0], sc[mt][nt][1]);
                w1[mt][nt] = cvtpk_bf16(sc[mt][nt][2], sc[mt][nt][3]);
            }
            s += __shfl_xor(s, 16);
            s += __shfl_xor(s, 32);
            lrn[nt] += s;
        }

        // ---- in-register P repack to B-operand layout + O += V^T P ----
        #pragma unroll
        for (int ks = 0; ks < 2; ks++) {
            short8 vf[4];
            #pragma unroll
            for (int dt = 0; dt < 4; dt++)
                vf[dt] = *(const short8*)(vbase + (size_t)(dt * 16 + l15) * S_LEN + kv0 + ks * 32 + hi * 8);
            #pragma unroll
            for (int nt = 0; nt < 2; nt++) {
                u32 a0 = (hi & 1) ? w0[2 * ks + 1][nt] : w0[2 * ks][nt];
                u32 a1 = (hi & 1) ? w1[2 * ks + 1][nt] : w1[2 * ks][nt];
                u32 b0 = (hi & 1) ? w0[2 * ks][nt] : w0[2 * ks + 1][nt];
                u32 b1 = (hi & 1) ? w1[2 * ks][nt] : w1[2 * ks + 1][nt];
                u32 r0 = (u32)__shfl((int)a0, laneA);
                u32 r1 = (u32)__shfl((int)a1, laneA);
                u32 r2 = (u32)__shfl((int)b0, laneB);
                u32 r3 = (u32)__shfl((int)b1, laneB);
                u32x4 pw;
                pw[0] = top ? r2 : r0;
                pw[1] = top ? r3 : r1;
                pw[2] = top ? r0 : r2;
                pw[3] = top ? r1 : r3;
                short8 pa = __builtin_bit_cast(short8, pw);
                #pragma unroll
                for (int dt = 0; dt < 4; dt++)
                    o[dt][nt] = __builtin_amdgcn_mfma_f32_16x16x32_bf16(vf[dt], pa, o[dt][nt], 0, 0, 0);
            }
        }
    }

    // ---- normalize + write (O^T layout: row=d, col=q) ----
    #pragma unroll
    for (int nt = 0; nt < 2; nt++) {
        float inv = 1.0f / lrn[nt];
        size_t rbase = (size_t)(qrow0 + nt * 16 + l15) * EMB + h * HD;
        #pragma unroll
        for (int dt = 0; dt < 4; dt++) {
            ushort4 pk;
            pk.x = f2bf(o[dt][nt][0] * inv);
            pk.y = f2bf(o[dt][nt][1] * inv);
            pk.z = f2bf(o[dt][nt][2] * inv);
            pk.w = f2bf(o[dt][nt][3] * inv);
            *(ushort4*)(out + rbase + dt * 16 + hi * 4) = pk;
        }
    }
}

extern "C" void kernel_launch(void* const* d_in, const int* in_sizes, int n_in,
                              void* d_out, int out_size, void* d_ws, size_t ws_size,
                              hipStream_t stream) {
    const float* datas = (const float*)d_in[0];
    const float* Wq = (const float*)d_in[1];
    const float* bq = (const float*)d_in[2];
    const float* Wk = (const float*)d_in[3];
    const float* bk = (const float*)d_in[4];
    const float* Wv = (const float*)d_in[5];
    const float* bv = (const float*)d_in[6];
    const float* Wo = (const float*)d_in[7];
    const float* bo = (const float*)d_in[8];
    float* out = (float*)d_out;

    char* ws = (char*)d_ws;
    unsigned short* Xb = (unsigned short*)ws;      ws += (size_t)MTOT * KDIM * 2;
    unsigned short* Wqkvt = (unsigned short*)ws;   ws += (size_t)NQKV * KDIM * 2;
    unsigned short* Wot = (unsigned short*)ws;     ws += (size_t)EMB * KDIM * 2;
    float* biasq = (float*)ws;                     ws += (size_t)NQKV * 4;
    unsigned short* QKV = (unsigned short*)ws;     ws += (size_t)MTOT * NQKV * 2;
    unsigned short* Vt = (unsigned short*)ws;      ws += (size_t)2 * NKVH * HD * S_LEN * 2;
    unsigned short* AO = (unsigned short*)ws;      ws += (size_t)MTOT * EMB * 2;

    cvt_x<<<2048, 256, 0, stream>>>(datas, Xb, MTOT * KDIM / 4);
    cat_bias<<<NQKV / 256, 256, 0, stream>>>(bq, bk, bv, biasq);
    transpose_w<<<dim3(EMB / 64, KDIM / 64), 256, 0, stream>>>(Wq, Wqkvt, EMB, 0);
    transpose_w<<<dim3(512 / 64, KDIM / 64), 256, 0, stream>>>(Wk, Wqkvt, 512, EMB);
    transpose_w<<<dim3(512 / 64, KDIM / 64), 256, 0, stream>>>(Wv, Wqkvt, 512, EMB + 512);
    transpose_w<<<dim3(EMB / 64, KDIM / 64), 256, 0, stream>>>(Wo, Wot, EMB, 0);

    gemm_bt<true><<<dim3(NQKV / 128, MTOT / 128), 256, 0, stream>>>(Xb, Wqkvt, biasq, QKV, NQKV);
    transpose_v<<<dim3(S_LEN / 64, NKVH, 2), 256, 0, stream>>>(QKV, Vt);
    attn<<<dim3(S_LEN / 128, NH, 2), 256, 0, stream>>>(QKV, Vt, AO);
    gemm_bt<false><<<dim3(EMB / 128, MTOT / 128), 256, 0, stream>>>(AO, Wot, bo, out, EMB);
}

// Round 3
// 314.162 us; speedup vs baseline: 1.3103x; 1.2354x over previous
//
#include <hip/hip_runtime.h>
#include <hip/hip_bf16.h>
#include <stdint.h>

// GQA prefill, all GEMM-shaped work on bf16 MFMA (16x16x32), fp32 accum.
// B=2 S=2048 E=2048 H=32 KVH=8 D=64 G=4.
// R3: attn K/V staged through double-buffered LDS (global_load_lds w=16,
//     source-side XOR swizzle so ds_read_b128 covers all 32 banks),
//     2-phase prefetch pipeline; swapped QK^T + in-reg softmax kept.

#define S_LEN 2048
#define EMB   2048
#define NH    32
#define NKVH  8
#define HD    64
#define MTOT  4096            // B*S
#define NQKV  3072            // E + 2*KVH*D
#define KDIM  2048

typedef __attribute__((ext_vector_type(8))) short short8;
typedef __attribute__((ext_vector_type(4))) float f32x4;
typedef __attribute__((ext_vector_type(4))) unsigned int u32x4;
typedef unsigned int u32;

__device__ __forceinline__ unsigned short f2bf(float x) {
    unsigned int u = __builtin_bit_cast(unsigned int, x);
    u = (u + 0x7FFFu + ((u >> 16) & 1u)) >> 16;   // RTN-even
    return (unsigned short)u;
}

// v_cvt_pk_bf16_f32: low16 = bf16(a), high16 = bf16(b)
__device__ __forceinline__ u32 cvtpk_bf16(float a, float b) {
    u32 r;
    asm("v_cvt_pk_bf16_f32 %0, %1, %2" : "=v"(r) : "v"(a), "v"(b));
    return r;
}

// ---------------- fp32 -> bf16 elementwise (X) ----------------
__global__ void cvt_x(const float* __restrict__ x, unsigned short* __restrict__ o, int n4) {
    int stride = gridDim.x * blockDim.x;
    for (int i = blockIdx.x * blockDim.x + threadIdx.x; i < n4; i += stride) {
        float4 v = ((const float4*)x)[i];
        ushort4 r;
        r.x = f2bf(v.x); r.y = f2bf(v.y); r.z = f2bf(v.z); r.w = f2bf(v.w);
        ((ushort4*)o)[i] = r;
    }
}

__global__ void cat_bias(const float* __restrict__ bq, const float* __restrict__ bk,
                         const float* __restrict__ bv, float* __restrict__ o) {
    int i = blockIdx.x * blockDim.x + threadIdx.x;
    if (i < EMB) o[i] = bq[i];
    else if (i < EMB + 512) o[i] = bk[i - EMB];
    else if (i < NQKV) o[i] = bv[i - EMB - 512];
}

// --------- transpose fp32 [K=2048][N] -> bf16 [N][2048] (+row offset) ---------
__global__ void transpose_w(const float* __restrict__ src, unsigned short* __restrict__ dst,
                            int N, int rowOfs) {
    __shared__ float t[64][65];
    int n0 = blockIdx.x * 64, k0 = blockIdx.y * 64;
    int c = threadIdx.x & 63, r0 = threadIdx.x >> 6;
    #pragma unroll
    for (int r = r0; r < 64; r += 4) t[r][c] = src[(size_t)(k0 + r) * N + n0 + c];
    __syncthreads();
    #pragma unroll
    for (int r = r0; r < 64; r += 4)
        dst[(size_t)(rowOfs + n0 + r) * KDIM + k0 + c] = f2bf(t[c][r]);
}

// --------- transpose V slice of QKV -> Vt[b][kvh][d][s] (bf16) ---------
__global__ void transpose_v(const unsigned short* __restrict__ qkv, unsigned short* __restrict__ vt) {
    __shared__ unsigned short t[64][72];
    int s0 = blockIdx.x * 64; int kvh = blockIdx.y; int b = blockIdx.z;
    int c = threadIdx.x & 63, r0 = threadIdx.x >> 6;
    #pragma unroll
    for (int r = r0; r < 64; r += 4)
        t[r][c] = qkv[(size_t)(b * S_LEN + s0 + r) * NQKV + (EMB + NKVH * HD) + kvh * HD + c];
    __syncthreads();
    #pragma unroll
    for (int r = r0; r < 64; r += 4)
        vt[(size_t)((b * NKVH + kvh) * HD + r) * S_LEN + s0 + c] = t[c][r];
}

// --------- bf16 GEMM: A[M][2048] * Bt[N][2048]^T + bias -> C[M][N] ---------
template <bool OUT_BF16>
__global__ __launch_bounds__(256) void gemm_bt(const unsigned short* __restrict__ A,
                                               const unsigned short* __restrict__ Bt,
                                               const float* __restrict__ bias,
                                               void* __restrict__ Cout, int N) {
    __shared__ __align__(16) unsigned short As[128 * 32];
    __shared__ __align__(16) unsigned short Bs[128 * 32];
    const int t = threadIdx.x;
    const int lane = t & 63;
    const int l15 = lane & 15, hi = lane >> 4;
    const int w = t >> 6;
    const int wm = (w >> 1) * 64, wn = (w & 1) * 64;
    const int m0 = blockIdx.y * 128, n0 = blockIdx.x * 128;

    const int srow = t >> 2, scol = (t & 3) * 8;
    const unsigned short* ag0 = A + (size_t)(m0 + srow) * KDIM + scol;
    const unsigned short* ag1 = ag0 + (size_t)64 * KDIM;
    const unsigned short* bg0 = Bt + (size_t)(n0 + srow) * KDIM + scol;
    const unsigned short* bg1 = bg0 + (size_t)64 * KDIM;

    f32x4 acc[4][4] = {};

    for (int k0 = 0; k0 < KDIM; k0 += 32) {
        __builtin_amdgcn_global_load_lds((const __attribute__((address_space(1))) void*)(ag0 + k0),
                                         (__attribute__((address_space(3))) void*)(As + t * 8), 16, 0, 0);
        __builtin_amdgcn_global_load_lds((const __attribute__((address_space(1))) void*)(ag1 + k0),
                                         (__attribute__((address_space(3))) void*)(As + 2048 + t * 8), 16, 0, 0);
        __builtin_amdgcn_global_load_lds((const __attribute__((address_space(1))) void*)(bg0 + k0),
                                         (__attribute__((address_space(3))) void*)(Bs + t * 8), 16, 0, 0);
        __builtin_amdgcn_global_load_lds((const __attribute__((address_space(1))) void*)(bg1 + k0),
                                         (__attribute__((address_space(3))) void*)(Bs + 2048 + t * 8), 16, 0, 0);
        __syncthreads();
        short8 af[4], bf[4];
        #pragma unroll
        for (int m = 0; m < 4; m++)
            af[m] = *(const short8*)(As + (wm + m * 16 + l15) * 32 + hi * 8);
        #pragma unroll
        for (int n = 0; n < 4; n++)
            bf[n] = *(const short8*)(Bs + (wn + n * 16 + l15) * 32 + hi * 8);
        #pragma unroll
        for (int m = 0; m < 4; m++)
            #pragma unroll
            for (int n = 0; n < 4; n++)
                acc[m][n] = __builtin_amdgcn_mfma_f32_16x16x32_bf16(af[m], bf[n], acc[m][n], 0, 0, 0);
        __syncthreads();
    }

    #pragma unroll
    for (int m = 0; m < 4; m++) {
        int row = m0 + wm + m * 16 + hi * 4;
        #pragma unroll
        for (int n = 0; n < 4; n++) {
            int col = n0 + wn + n * 16 + l15;
            float bb = bias[col];
            #pragma unroll
            for (int i = 0; i < 4; i++) {
                float v = acc[m][n][i] + bb;
                if (OUT_BF16) ((unsigned short*)Cout)[(size_t)(row + i) * N + col] = f2bf(v);
                else          ((float*)Cout)[(size_t)(row + i) * N + col] = v;
            }
        }
    }
}

// --------- flash attention: LDS-staged K/V (dbuf), swapped QK^T, no-LDS softmax ---------
// Per wave: 32 q rows (2 n-tiles of 16), KV tile 64 (4 m-tiles of 16).
// LDS tile layout: row r (64 rows, 128B each) has 8 16B slots; slot sl holds
// global column-16B (sl ^ (r&7)). global_load_lds dest stays linear (rule #21):
// thread t -> dest slot (r=t>>3, sl=t&7), source col16 = (t&7)^(r&7).
__global__ __launch_bounds__(256) void attn(const unsigned short* __restrict__ qkv,
                                            const unsigned short* __restrict__ vt,
                                            unsigned short* __restrict__ out) {
    constexpr float CEXP = 0.125f * 1.4426950408889634f;   // scale * log2(e)
    constexpr int NT = S_LEN / 64;
    const int qt = blockIdx.x, h = blockIdx.y, b = blockIdx.z;
    const int kvh = h >> 2;
    const int t = threadIdx.x, lane = t & 63, w = t >> 6;
    const int l15 = lane & 15, hi = lane >> 4;
    const int xsw = l15 & 7;

    __shared__ __align__(16) unsigned short Ks[2][64 * 64];
    __shared__ __align__(16) unsigned short Vs[2][64 * 64];

    // bpermute source lanes for the P repack
    const int grpA = ((hi & 1) << 1) | (hi >> 1);
    const int laneA = l15 + grpA * 16;
    const int laneB = laneA ^ 16;
    const bool top = hi >= 2;

    const int qrow0 = b * S_LEN + qt * 128 + w * 32;
    short8 qf[2][2];  // [nt][ks]
    #pragma unroll
    for (int nt = 0; nt < 2; nt++)
        #pragma unroll
        for (int ks = 0; ks < 2; ks++)
            qf[nt][ks] = *(const short8*)(qkv + (size_t)(qrow0 + nt * 16 + l15) * NQKV + h * HD + ks * 32 + hi * 8);

    f32x4 o[4][2] = {};              // [dt][nt]
    float mrn[2] = {-__builtin_inff(), -__builtin_inff()};
    float lrn[2] = {0.f, 0.f};

    const unsigned short* kbase = qkv + (size_t)b * S_LEN * NQKV + EMB + kvh * HD;
    const unsigned short* vbase = vt + (size_t)(b * NKVH + kvh) * HD * S_LEN;

    // staging source pointers for this thread
    const int sr = t >> 3;                       // dest row (0..31) within half
    const int sc16 = ((t & 7) ^ (sr & 7)) * 8;   // pre-swizzled source col (shorts)
    const unsigned short* kg0 = kbase + (size_t)sr * NQKV + sc16;
    const unsigned short* kg1 = kbase + (size_t)(sr + 32) * NQKV + sc16;
    const unsigned short* vg0 = vbase + (size_t)sr * S_LEN + sc16;
    const unsigned short* vg1 = vbase + (size_t)(sr + 32) * S_LEN + sc16;

#define STAGE(buf, kv0)                                                                             \
    do {                                                                                            \
        __builtin_amdgcn_global_load_lds((const __attribute__((address_space(1))) void*)(kg0 + (size_t)(kv0) * NQKV), \
                                         (__attribute__((address_space(3))) void*)(&Ks[buf][t * 8]), 16, 0, 0);       \
        __builtin_amdgcn_global_load_lds((const __attribute__((address_space(1))) void*)(kg1 + (size_t)(kv0) * NQKV), \
                                         (__attribute__((address_space(3))) void*)(&Ks[buf][2048 + t * 8]), 16, 0, 0);\
        __builtin_amdgcn_global_load_lds((const __attribute__((address_space(1))) void*)(vg0 + (kv0)),                \
                                         (__attribute__((address_space(3))) void*)(&Vs[buf][t * 8]), 16, 0, 0);       \
        __builtin_amdgcn_global_load_lds((const __attribute__((address_space(1))) void*)(vg1 + (kv0)),                \
                                         (__attribute__((address_space(3))) void*)(&Vs[buf][2048 + t * 8]), 16, 0, 0);\
    } while (0)

    STAGE(0, 0);
    __syncthreads();

    for (int tt = 0; tt < NT; tt++) {
        const int cur = tt & 1;
        if (tt + 1 < NT) STAGE(cur ^ 1, (tt + 1) * 64);

        const unsigned short* Kc = Ks[cur];
        const unsigned short* Vc = Vs[cur];

        // ---- S^T = K Q^T ----
        f32x4 sc[4][2] = {};         // [mt(k)][nt(q)]
        #pragma unroll
        for (int ks = 0; ks < 2; ks++) {
            short8 kf[4];
            #pragma unroll
            for (int mt = 0; mt < 4; mt++)
                kf[mt] = *(const short8*)(Kc + (mt * 16 + l15) * 64 + (((ks * 4 + hi) ^ xsw) * 8));
            #pragma unroll
            for (int mt = 0; mt < 4; mt++)
                #pragma unroll
                for (int nt = 0; nt < 2; nt++)
                    sc[mt][nt] = __builtin_amdgcn_mfma_f32_16x16x32_bf16(kf[mt], qf[nt][ks], sc[mt][nt], 0, 0, 0);
        }

        // ---- online softmax, lane-local over k ----
        u32 w0[4][2], w1[4][2];      // packed bf16 P pairs [mt][nt]
        #pragma unroll
        for (int nt = 0; nt < 2; nt++) {
            float m01 = fmaxf(fmaxf(sc[0][nt][0], sc[0][nt][1]), fmaxf(sc[0][nt][2], sc[0][nt][3]));
            float m23 = fmaxf(fmaxf(sc[1][nt][0], sc[1][nt][1]), fmaxf(sc[1][nt][2], sc[1][nt][3]));
            float m45 = fmaxf(fmaxf(sc[2][nt][0], sc[2][nt][1]), fmaxf(sc[2][nt][2], sc[2][nt][3]));
            float m67 = fmaxf(fmaxf(sc[3][nt][0], sc[3][nt][1]), fmaxf(sc[3][nt][2], sc[3][nt][3]));
            float mx = fmaxf(fmaxf(m01, m23), fmaxf(m45, m67));
            mx = fmaxf(mx, __shfl_xor(mx, 16));
            mx = fmaxf(mx, __shfl_xor(mx, 32));
            // defer-max: only rescale when the new tile max exceeds by >16 (raw units)
            if (!__all(mx - mrn[nt] <= 16.f)) {
                float mn = fmaxf(mrn[nt], mx);
                float fac = exp2f((mrn[nt] - mn) * CEXP);
                lrn[nt] *= fac;
                #pragma unroll
                for (int dt = 0; dt < 4; dt++)
                    o[dt][nt] *= fac;
                mrn[nt] = mn;
            }
            float s = 0.f;
            #pragma unroll
            for (int mt = 0; mt < 4; mt++) {
                #pragma unroll
                for (int i = 0; i < 4; i++) {
                    float p = exp2f((sc[mt][nt][i] - mrn[nt]) * CEXP);
                    sc[mt][nt][i] = p;
                    s += p;
                }
                w0[mt][nt] = cvtpk_bf16(sc[mt][nt][0], sc[mt][nt][1]);
                w1[mt][nt] = cvtpk_bf16(sc[mt][nt][2], sc[mt][nt][3]);
            }
            s += __shfl_xor(s, 16);
            s += __shfl_xor(s, 32);
            lrn[nt] += s;
        }

        // ---- in-register P repack to B-operand layout + O += V^T P ----
        #pragma unroll
        for (int ks = 0; ks < 2; ks++) {
            short8 vf[4];
            #pragma unroll
            for (int dt = 0; dt < 4; dt++)
                vf[dt] = *(const short8*)(Vc + (dt * 16 + l15) * 64 + (((ks * 4 + hi) ^ xsw) * 8));
            #pragma unroll
            for (int nt = 0; nt < 2; nt++) {
                u32 a0 = (hi & 1) ? w0[2 * ks + 1][nt] : w0[2 * ks][nt];
                u32 a1 = (hi & 1) ? w1[2 * ks + 1][nt] : w1[2 * ks][nt];
                u32 b0 = (hi & 1) ? w0[2 * ks][nt] : w0[2 * ks + 1][nt];
                u32 b1 = (hi & 1) ? w1[2 * ks][nt] : w1[2 * ks + 1][nt];
                u32 r0 = (u32)__shfl((int)a0, laneA);
                u32 r1 = (u32)__shfl((int)a1, laneA);
                u32 r2 = (u32)__shfl((int)b0, laneB);
                u32 r3 = (u32)__shfl((int)b1, laneB);
                u32x4 pw;
                pw[0] = top ? r2 : r0;
                pw[1] = top ? r3 : r1;
                pw[2] = top ? r0 : r2;
                pw[3] = top ? r1 : r3;
                short8 pa = __builtin_bit_cast(short8, pw);
                #pragma unroll
                for (int dt = 0; dt < 4; dt++)
                    o[dt][nt] = __builtin_amdgcn_mfma_f32_16x16x32_bf16(vf[dt], pa, o[dt][nt], 0, 0, 0);
            }
        }
        __syncthreads();   // drains stage(tt+1) vmem; protects buffer reuse
    }
#undef STAGE

    // ---- normalize + write (O^T layout: row=d, col=q) ----
    #pragma unroll
    for (int nt = 0; nt < 2; nt++) {
        float inv = 1.0f / lrn[nt];
        size_t rbase = (size_t)(qrow0 + nt * 16 + l15) * EMB + h * HD;
        #pragma unroll
        for (int dt = 0; dt < 4; dt++) {
            ushort4 pk;
            pk.x = f2bf(o[dt][nt][0] * inv);
            pk.y = f2bf(o[dt][nt][1] * inv);
            pk.z = f2bf(o[dt][nt][2] * inv);
            pk.w = f2bf(o[dt][nt][3] * inv);
            *(ushort4*)(out + rbase + dt * 16 + hi * 4) = pk;
        }
    }
}

extern "C" void kernel_launch(void* const* d_in, const int* in_sizes, int n_in,
                              void* d_out, int out_size, void* d_ws, size_t ws_size,
                              hipStream_t stream) {
    const float* datas = (const float*)d_in[0];
    const float* Wq = (const float*)d_in[1];
    const float* bq = (const float*)d_in[2];
    const float* Wk = (const float*)d_in[3];
    const float* bk = (const float*)d_in[4];
    const float* Wv = (const float*)d_in[5];
    const float* bv = (const float*)d_in[6];
    const float* Wo = (const float*)d_in[7];
    const float* bo = (const float*)d_in[8];
    float* out = (float*)d_out;

    char* ws = (char*)d_ws;
    unsigned short* Xb = (unsigned short*)ws;      ws += (size_t)MTOT * KDIM * 2;
    unsigned short* Wqkvt = (unsigned short*)ws;   ws += (size_t)NQKV * KDIM * 2;
    unsigned short* Wot = (unsigned short*)ws;     ws += (size_t)EMB * KDIM * 2;
    float* biasq = (float*)ws;                     ws += (size_t)NQKV * 4;
    unsigned short* QKV = (unsigned short*)ws;     ws += (size_t)MTOT * NQKV * 2;
    unsigned short* Vt = (unsigned short*)ws;      ws += (size_t)2 * NKVH * HD * S_LEN * 2;
    unsigned short* AO = (unsigned short*)ws;      ws += (size_t)MTOT * EMB * 2;

    cvt_x<<<2048, 256, 0, stream>>>(datas, Xb, MTOT * KDIM / 4);
    cat_bias<<<NQKV / 256, 256, 0, stream>>>(bq, bk, bv, biasq);
    transpose_w<<<dim3(EMB / 64, KDIM / 64), 256, 0, stream>>>(Wq, Wqkvt, EMB, 0);
    transpose_w<<<dim3(512 / 64, KDIM / 64), 256, 0, stream>>>(Wk, Wqkvt, 512, EMB);
    transpose_w<<<dim3(512 / 64, KDIM / 64), 256, 0, stream>>>(Wv, Wqkvt, 512, EMB + 512);
    transpose_w<<<dim3(EMB / 64, KDIM / 64), 256, 0, stream>>>(Wo, Wot, EMB, 0);

    gemm_bt<true><<<dim3(NQKV / 128, MTOT / 128), 256, 0, stream>>>(Xb, Wqkvt, biasq, QKV, NQKV);
    transpose_v<<<dim3(S_LEN / 64, NKVH, 2), 256, 0, stream>>>(QKV, Vt);
    attn<<<dim3(S_LEN / 128, NH, 2), 256, 0, stream>>>(QKV, Vt, AO);
    gemm_bt<false><<<dim3(EMB / 128, MTOT / 128), 256, 0, stream>>>(AO, Wot, bo, out, EMB);
}